// Round 3
// baseline (259.332 us; speedup 1.0000x reference)
//
#include <hip/hip_runtime.h>
#include <cstdint>
#include <cstddef>

#define NF 256   // features
#define NG 512   // hidden (2F)
#define NC 64    // classes
#define NB 8192  // batch
#define NK 16    // active rules
#define BT 64    // fs batch tile
#define SM 264   // LDS row stride in shorts (264*2=528 B, 8B-aligned, 132 dwords -> +4 banks/row)

typedef __attribute__((ext_vector_type(8))) short short8;
typedef __attribute__((ext_vector_type(4))) float floatx4;

__device__ __forceinline__ unsigned short f2bf(float f) {
    union { float f; unsigned int u; } a; a.f = f;
    unsigned int u = a.u;
    u += 0x7fffu + ((u >> 16) & 1u);   // RNE (used only in cold conv kernel)
    return (unsigned short)(u >> 16);
}
// round-half-up bf16 pair pack: low short = a, high short = b
__device__ __forceinline__ unsigned int packbf2(float a, float b) {
    unsigned int ua = __float_as_uint(a), ub = __float_as_uint(b);
    return ((ua + 0x8000u) >> 16) | ((ub + 0x8000u) & 0xffff0000u);
}
__device__ __forceinline__ float elu1(float z) {
    return z > 0.0f ? z : (__expf(z) - 1.0f);
}

// ---------------- kernel 0: weights fp32 -> bf16 in workspace ----------------
// layout (ushort elements): [0,131072) W1b | [131072,262144) W2b | [262144,786432) Wcb
__global__ __launch_bounds__(256) void conv_kernel(
    const float* __restrict__ W1, const float* __restrict__ W2,
    const float* __restrict__ Wc, unsigned short* __restrict__ wb)
{
    int i = blockIdx.x * 256 + threadIdx.x;
    if (i < 131072)       wb[i] = f2bf(W1[i]);
    else if (i < 262144)  wb[i] = f2bf(W2[i - 131072]);
    else if (i < 786432)  wb[i] = f2bf(Wc[i - 262144]);
}

// ---------------- kernel 1: fused membership -> MLP -> fsi ----------------
// grid: 2048 blocks = 16 rules x 128 batch tiles; 512 threads (8 waves)
// LDS: mv [64][SM] + cb [64][SM] = 67584 B -> 2 blocks/CU (16 waves/CU),
// VGPR capped at 128 via __launch_bounds__(512,4); explicit depth-1 global
// prefetch uses the headroom the round-1 compiler left idle (it chose 64).
// Phase 1 computes D TRANSPOSED (a=W1 so m=n_out, n=batch): the C-layout
// register axis (4 consecutive rows) becomes 4 consecutive h1 columns ->
// ELU stores are 8x ds_write_b64 per thread/chunk instead of 32x ds_write_b16.
__global__ __launch_bounds__(512, 4) void fs_kernel(
    const float* __restrict__ x, const float* __restrict__ proto,
    const float* __restrict__ var, const unsigned short* __restrict__ W1b,
    const float* __restrict__ b1, const unsigned short* __restrict__ W2b,
    const float* __restrict__ b2, const float* __restrict__ W3,
    const float* __restrict__ b3, const int* __restrict__ ridx,
    float* __restrict__ fsi)
{
    extern __shared__ unsigned short smem[];
    unsigned short* mv = smem;            // [64][SM]  (batch-major membership)
    unsigned short* cb = smem + 64 * SM;  // [64][SM]  h1 chunk buffer / part[]

    const int t    = threadIdx.x;
    const int kidx = blockIdx.x & 15;
    const int tile = blockIdx.x >> 4;
    const int r    = ridx[kidx];
    const int b0   = tile * BT;

    // ---- phase 0: mv = exp(-(x-p)^2 / (2 v^2)), v=clip(var,1e-4,0.1) ----
    {
        const int col   = (t & 63) * 4;
        const int rbase = t >> 6;           // 0..7
        const float4 p4 = *(const float4*)(proto + (size_t)r * NF + col);
        float4 v4 = *(const float4*)(var + (size_t)r * NF + col);
        float cx = fminf(fmaxf(v4.x, 1e-4f), 0.1f);
        float cy = fminf(fmaxf(v4.y, 1e-4f), 0.1f);
        float cz = fminf(fmaxf(v4.z, 1e-4f), 0.1f);
        float cw = fminf(fmaxf(v4.w, 1e-4f), 0.1f);
        float ix = 0.5f / (cx * cx), iy = 0.5f / (cy * cy);
        float iz = 0.5f / (cz * cz), iw = 0.5f / (cw * cw);
#pragma unroll
        for (int i = 0; i < 8; ++i) {
            int row = i * 8 + rbase;
            const float4 xv = *(const float4*)(x + (size_t)(b0 + row) * NF + col);
            float dx = xv.x - p4.x, dy = xv.y - p4.y, dz = xv.z - p4.z, dw = xv.w - p4.w;
            uint2 pk;
            pk.x = packbf2(__expf(-dx * dx * ix), __expf(-dy * dy * iy));
            pk.y = packbf2(__expf(-dz * dz * iz), __expf(-dw * dw * iw));
            *(uint2*)(mv + row * SM + col) = pk;
        }
    }
    __syncthreads();

    const int wave = t >> 6, lane = t & 63;
    const int ln = lane & 15, lq = lane >> 4;

    // persistent h2 accumulator: wave n2-tile = 32 (8 waves x 32 = 256... NG? no:
    // phase-2 output h2 has 256 cols; wave covers 32). row=batch, col=n2.
    floatx4 acc2[4][2];
#pragma unroll
    for (int mi = 0; mi < 4; ++mi)
#pragma unroll
        for (int ni = 0; ni < 2; ++ni) {
            floatx4 z = {0.0f, 0.0f, 0.0f, 0.0f};
            acc2[mi][ni] = z;
        }

    for (int c = 0; c < 2; ++c) {
        // ---- phase 1 (chunk c): h1 cols [c*256, c*256+256), TRANSPOSED D ----
        // wave tile: m = 32 n_out (2 frags, W1 global), n = 64 batch (4 frags, mv LDS)
        floatx4 acc1[2][4];
#pragma unroll
        for (int mt = 0; mt < 2; ++mt)
#pragma unroll
            for (int nt = 0; nt < 4; ++nt) {
                floatx4 z = {0.0f, 0.0f, 0.0f, 0.0f};
                acc1[mt][nt] = z;
            }
        {
            const unsigned short* wA0 =
                W1b + (size_t)(c * 256 + wave * 32 + ln) * NF + lq * 8;
            const unsigned short* wA1 = wA0 + 16 * NF;
            short8 a0 = *(const short8*)(wA0);
            short8 a1 = *(const short8*)(wA1);
#pragma unroll
            for (int k0i = 0; k0i < 8; ++k0i) {
                short8 a0n = a0, a1n = a1;
                if (k0i < 7) {                       // depth-1 global prefetch
                    a0n = *(const short8*)(wA0 + (k0i + 1) * 32);
                    a1n = *(const short8*)(wA1 + (k0i + 1) * 32);
                }
                short8 bm[4];
#pragma unroll
                for (int nt = 0; nt < 4; ++nt)
                    bm[nt] = *(const short8*)(mv + (nt * 16 + ln) * SM + k0i * 32 + lq * 8);
#pragma unroll
                for (int nt = 0; nt < 4; ++nt) {
                    acc1[0][nt] = __builtin_amdgcn_mfma_f32_16x16x32_bf16(a0, bm[nt], acc1[0][nt], 0, 0, 0);
                    acc1[1][nt] = __builtin_amdgcn_mfma_f32_16x16x32_bf16(a1, bm[nt], acc1[1][nt], 0, 0, 0);
                }
                a0 = a0n; a1 = a1n;
            }
        }
        __syncthreads();   // prior chunk's phase-2 reads of cb are done
        // ELU + bias; D row (= register axis) is n_out -> 4 contiguous cols, b64 stores
#pragma unroll
        for (int mt = 0; mt < 2; ++mt) {
            const int nout = wave * 32 + mt * 16 + lq * 4;   // chunk-local h1 col base
            const float4 bias = *(const float4*)(b1 + c * 256 + nout);
#pragma unroll
            for (int nt = 0; nt < 4; ++nt) {
                float z0 = elu1(acc1[mt][nt][0] + bias.x);
                float z1 = elu1(acc1[mt][nt][1] + bias.y);
                float z2 = elu1(acc1[mt][nt][2] + bias.z);
                float z3 = elu1(acc1[mt][nt][3] + bias.w);
                uint2 pk;
                pk.x = packbf2(z0, z1);
                pk.y = packbf2(z2, z3);
                *(uint2*)(cb + (nt * 16 + ln) * SM + nout) = pk;
            }
        }
        __syncthreads();
        // ---- phase 2 (chunk c): acc2 += cb @ W2[:, c*256:+256]^T ----
        // a = cb rows (batch, LDS), b = W2 rows (n2, global, depth-1 prefetch)
        {
            const unsigned short* wB =
                W2b + (size_t)(wave * 32 + ln) * NG + c * 256 + lq * 8;
            short8 bf0 = *(const short8*)(wB);
            short8 bf1 = *(const short8*)(wB + 16 * NG);
#pragma unroll
            for (int k0i = 0; k0i < 8; ++k0i) {
                short8 b0n = bf0, b1n = bf1;
                if (k0i < 7) {
                    b0n = *(const short8*)(wB + (k0i + 1) * 32);
                    b1n = *(const short8*)(wB + 16 * NG + (k0i + 1) * 32);
                }
                short8 am[4];
#pragma unroll
                for (int mt = 0; mt < 4; ++mt)
                    am[mt] = *(const short8*)(cb + (mt * 16 + ln) * SM + k0i * 32 + lq * 8);
#pragma unroll
                for (int mt = 0; mt < 4; ++mt) {
                    acc2[mt][0] = __builtin_amdgcn_mfma_f32_16x16x32_bf16(am[mt], bf0, acc2[mt][0], 0, 0, 0);
                    acc2[mt][1] = __builtin_amdgcn_mfma_f32_16x16x32_bf16(am[mt], bf1, acc2[mt][1], 0, 0, 0);
                }
                bf0 = b0n; bf1 = b1n;
            }
        }
    }

    // ---- phase 3: fsi[b] = ELU(h2)[b,:] . W3 + b3 (h2 in registers, fp32) ----
    __syncthreads();                 // cb reads done; reuse cb as float part[8][64]
    float* part = (float*)cb;
    float bb[2], ww[2];
#pragma unroll
    for (int ni = 0; ni < 2; ++ni) {
        int n = wave * 32 + ni * 16 + ln;
        bb[ni] = b2[n];
        ww[ni] = W3[n];
    }
#pragma unroll
    for (int mi = 0; mi < 4; ++mi)
#pragma unroll
        for (int rg = 0; rg < 4; ++rg) {
            float s = elu1(acc2[mi][0][rg] + bb[0]) * ww[0]
                    + elu1(acc2[mi][1][rg] + bb[1]) * ww[1];
            s += __shfl_xor(s, 1);
            s += __shfl_xor(s, 2);
            s += __shfl_xor(s, 4);
            s += __shfl_xor(s, 8);
            if (ln == 0) part[wave * 64 + mi * 16 + lq * 4 + rg] = s;
        }
    __syncthreads();
    if (t < 64) {
        float s = b3[0];
#pragma unroll
        for (int w = 0; w < 8; ++w) s += part[w * 64 + t];
        fsi[(size_t)kidx * NB + b0 + t] = s;
    }
}

// ---------------- kernel 2: softmax over rules + consequent + weighted sum ----------------
// grid: 512 blocks x 256 threads; block = 16 batch rows, wave w = 16 classes.
// k-outer loop with 16 INDEPENDENT per-rule MFMA chains (acc in 64 VGPR) —
// round-2's single 8-deep dependent chain per rule was latency-bound at
// 2 waves/SIMD. fire stored transposed [rule][row] for float4 epilogue reads.
__global__ __launch_bounds__(256, 2) void cons_kernel(
    const float* __restrict__ x, const unsigned short* __restrict__ Wcb,
    const float* __restrict__ bc, const float* __restrict__ fsi,
    const int* __restrict__ ridx, float* __restrict__ outp,
    float* __restrict__ fire_out)
{
    __shared__ unsigned short xl[16 * SM];
    __shared__ float fire[NK][16];     // [rule][row]

    const int t  = threadIdx.x;
    const int b0 = blockIdx.x * 16;

    // x -> bf16 LDS (16 rows)
    {
        const int col   = (t & 63) * 4;
        const int rbase = t >> 6;   // 0..3
#pragma unroll
        for (int i = 0; i < 4; ++i) {
            int row = i * 4 + rbase;
            const float4 xv = *(const float4*)(x + (size_t)(b0 + row) * NF + col);
            uint2 pk;
            pk.x = packbf2(xv.x, xv.y);
            pk.y = packbf2(xv.z, xv.w);
            *(uint2*)(xl + row * SM + col) = pk;
        }
    }
    // softmax over 16 rules, fully parallel: thread = (row = t>>4, k = t&15)
    {
        const int row = t >> 4, k = t & 15;
        float v = fsi[(size_t)k * NB + b0 + row];
        float mx = v;
        mx = fmaxf(mx, __shfl_xor(mx, 1));
        mx = fmaxf(mx, __shfl_xor(mx, 2));
        mx = fmaxf(mx, __shfl_xor(mx, 4));
        mx = fmaxf(mx, __shfl_xor(mx, 8));
        float e = __expf(v - mx);
        float sum = e;
        sum += __shfl_xor(sum, 1);
        sum += __shfl_xor(sum, 2);
        sum += __shfl_xor(sum, 4);
        sum += __shfl_xor(sum, 8);
        float fv = e / sum;
        fire[k][row] = fv;
        fire_out[(size_t)b0 * NK + t] = fv;   // (b0+row)*16 + k == b0*16 + t
    }
    __syncthreads();

    const int wave = t >> 6, lane = t & 63;
    const int ln = lane & 15, lq = lane >> 4;
    const int nb = wave * 16;

    // x fragments register-cached, reused across all 16 rules
    short8 afr[8];
#pragma unroll
    for (int k0i = 0; k0i < 8; ++k0i)
        afr[k0i] = *(const short8*)(xl + ln * SM + k0i * 32 + lq * 8);

    // per-rule weight row offsets (scalar)
    int rbase[NK];
#pragma unroll
    for (int k = 0; k < NK; ++k) rbase[k] = ridx[k] * (NC * NF);
    const int lofs = (nb + ln) * NF + lq * 8;

    floatx4 acc[NK];
#pragma unroll
    for (int k = 0; k < NK; ++k) {
        floatx4 z = {0.0f, 0.0f, 0.0f, 0.0f};
        acc[k] = z;
    }
#pragma unroll
    for (int k0i = 0; k0i < 8; ++k0i) {
        const short8 a = afr[k0i];
#pragma unroll
        for (int k = 0; k < NK; ++k) {
            short8 b = *(const short8*)(Wcb + rbase[k] + lofs + k0i * 32);
            acc[k] = __builtin_amdgcn_mfma_f32_16x16x32_bf16(a, b, acc[k], 0, 0, 0);
        }
    }

    floatx4 oacc = {0.0f, 0.0f, 0.0f, 0.0f};
#pragma unroll
    for (int k = 0; k < NK; ++k) {
        float bias = bc[(size_t)ridx[k] * NC + nb + ln];
        const float4 fv = *(const float4*)(&fire[k][lq * 4]);
        oacc[0] += fmaxf(acc[k][0] + bias, 0.0f) * fv.x;
        oacc[1] += fmaxf(acc[k][1] + bias, 0.0f) * fv.y;
        oacc[2] += fmaxf(acc[k][2] + bias, 0.0f) * fv.z;
        oacc[3] += fmaxf(acc[k][3] + bias, 0.0f) * fv.w;
    }
#pragma unroll
    for (int rg = 0; rg < 4; ++rg)
        outp[(size_t)(b0 + lq * 4 + rg) * NC + nb + ln] = oacc[rg];
}

extern "C" void kernel_launch(void* const* d_in, const int* in_sizes, int n_in,
                              void* d_out, int out_size, void* d_ws, size_t ws_size,
                              hipStream_t stream)
{
    (void)in_sizes; (void)n_in; (void)out_size;
    if (ws_size < 2097152) return;  // 1.5MB bf16 weights + 0.5MB fsi

    const float* x     = (const float*)d_in[0];
    const float* proto = (const float*)d_in[1];
    const float* var   = (const float*)d_in[2];
    const float* W1    = (const float*)d_in[3];
    const float* b1    = (const float*)d_in[4];
    const float* W2    = (const float*)d_in[5];
    const float* b2    = (const float*)d_in[6];
    const float* W3    = (const float*)d_in[7];
    const float* b3    = (const float*)d_in[8];
    const float* Wc    = (const float*)d_in[9];
    const float* bc    = (const float*)d_in[10];
    const int*   ridx  = (const int*)d_in[11];

    unsigned short* wb  = (unsigned short*)d_ws;
    unsigned short* W1b = wb;                 // 131072
    unsigned short* W2b = wb + 131072;        // 131072
    unsigned short* Wcb = wb + 262144;        // 524288
    float* fsi = (float*)((char*)d_ws + (size_t)786432 * 2);  // 16*8192 floats

    float* outp     = (float*)d_out;
    float* fire_out = outp + (size_t)NB * NC;

    conv_kernel<<<3072, 256, 0, stream>>>(W1, W2, Wc, wb);

    const int fs_lds = 2 * 64 * SM * 2;  // 67584 B
    hipFuncSetAttribute((const void*)fs_kernel,
                        hipFuncAttributeMaxDynamicSharedMemorySize, fs_lds);
    fs_kernel<<<2048, 512, fs_lds, stream>>>(x, proto, var, W1b, b1, W2b, b2,
                                             W3, b3, ridx, fsi);
    cons_kernel<<<512, 256, 0, stream>>>(x, Wcb, bc, fsi, ridx, outp, fire_out);
}